// Round 2
// baseline (326.534 us; speedup 1.0000x reference)
//
#include <hip/hip_runtime.h>

#define N_NODES 50000
#define N_EDGES 800000
#define D 128
#define TM 128      // rows per block in KH

__device__ __forceinline__ unsigned short f2bf(float f) {
    union { float f; unsigned u; } v; v.f = f;
    unsigned r = (v.u + 0x7fffu + ((v.u >> 16) & 1u)) >> 16;
    return (unsigned short)r;
}

// ---------------- KH: h_bf16 = X @ W (fp32 accum); a_src/a_dst epilogue -----
__global__ __launch_bounds__(256) void kh(const float* __restrict__ X,
                                          const float* __restrict__ W,
                                          const float* __restrict__ ka,
                                          unsigned short* __restrict__ h,
                                          float* __restrict__ a_src,
                                          float* __restrict__ a_dst,
                                          int n_rows) {
    __shared__ float Ws[D * D];      // [k][c], 64 KB
    __shared__ float As[TM * D];     // [r][k], 64 KB
    __shared__ float kas[2 * D];
    int tid = threadIdx.x;
    int row0 = blockIdx.x * TM;

    for (int i = tid; i < D * D / 4; i += 256)
        ((float4*)Ws)[i] = ((const float4*)W)[i];
    kas[tid] = ka[tid];                         // 256 threads, 256 elems
    for (int i = tid; i < TM * D / 4; i += 256) {
        int r = i >> 5;                         // 32 float4 per row
        int gr = row0 + r;
        float4 v = make_float4(0.f, 0.f, 0.f, 0.f);
        if (gr < n_rows) v = ((const float4*)(X + (size_t)gr * D))[i & 31];
        ((float4*)As)[i] = v;
    }
    __syncthreads();

    int cg = tid & 15;          // 16 col groups x 8 cols
    int rg = tid >> 4;          // 16 row groups x 8 rows
    int c0 = cg * 8;
    int r0 = rg * 8;
    float acc[8][8];
#pragma unroll
    for (int i = 0; i < 8; ++i)
#pragma unroll
        for (int j = 0; j < 8; ++j) acc[i][j] = 0.f;

    for (int k = 0; k < D; k += 4) {
        float4 av[8];
#pragma unroll
        for (int i = 0; i < 8; ++i)
            av[i] = *(const float4*)&As[(r0 + i) * D + k];
#pragma unroll
        for (int kk = 0; kk < 4; ++kk) {
            float4 wlo = *(const float4*)&Ws[(k + kk) * D + c0];
            float4 whi = *(const float4*)&Ws[(k + kk) * D + c0 + 4];
            float wv[8] = {wlo.x, wlo.y, wlo.z, wlo.w, whi.x, whi.y, whi.z, whi.w};
#pragma unroll
            for (int i = 0; i < 8; ++i) {
                float a = (kk == 0) ? av[i].x : (kk == 1) ? av[i].y
                        : (kk == 2) ? av[i].z : av[i].w;
#pragma unroll
                for (int j = 0; j < 8; ++j) acc[i][j] += a * wv[j];
            }
        }
    }

    // epilogue: bf16 h + per-row attention dots
#pragma unroll
    for (int i = 0; i < 8; ++i) {
        int row = row0 + r0 + i;
        float ps = 0.f, pd = 0.f;
#pragma unroll
        for (int j = 0; j < 8; ++j) {
            ps += acc[i][j] * kas[c0 + j];
            pd += acc[i][j] * kas[D + c0 + j];
        }
        for (int off = 8; off > 0; off >>= 1) {
            ps += __shfl_down(ps, off, 16);
            pd += __shfl_down(pd, off, 16);
        }
        if (row < n_rows) {
            union { unsigned short us[8]; uint4 q; } pk;
#pragma unroll
            for (int j = 0; j < 8; ++j) pk.us[j] = f2bf(acc[i][j]);
            *(uint4*)&h[(size_t)row * D + c0] = pk.q;
            if (cg == 0) { a_src[row] = ps; a_dst[row] = pd; }
        }
    }
}

// ---------------- K3: binary-search + segment gather over bf16 h ------------
#define CH 256
__global__ __launch_bounds__(256) void k3(const int* __restrict__ edges,
                                          const unsigned short* __restrict__ h,
                                          const float* __restrict__ a_src,
                                          const float* __restrict__ a_dst,
                                          float* __restrict__ out) {
    __shared__ float ss[CH];
    __shared__ int   sd[CH];
    __shared__ float2 red[4][64];
    __shared__ float dred[4];
    __shared__ int seg[2];
    int tid = threadIdx.x;
    int n = blockIdx.x;
    if (tid < 2) {
        int target = n + tid;
        int lo = 0, hi = N_EDGES;
        while (lo < hi) {
            int mid = (lo + hi) >> 1;
            if (edges[2 * mid] < target) lo = mid + 1; else hi = mid;
        }
        seg[tid] = lo;
    }
    __syncthreads();
    int start = seg[0], end = seg[1];
    int slot = tid >> 6, col = tid & 63;
    float2 acc = make_float2(0.f, 0.f);
    float dn = 0.f;
    float asn = a_src[n];

    for (int base = start; base < end; base += CH) {
        int cnt = min(CH, end - base);
        if (tid < cnt) {
            int d = edges[2 * (base + tid) + 1];
            float lg = asn + a_dst[d];
            lg = (lg >= 0.f) ? lg : 0.2f * lg;       // leaky_relu 0.2
            lg = fminf(fmaxf(lg, -2.f), 2.f);        // clip
            ss[tid] = __expf(lg);
            sd[tid] = d;
        }
        __syncthreads();
        for (int j = slot; j < cnt; j += 4) {
            float s = ss[j];
            unsigned p = *(const unsigned*)(h + ((size_t)sd[j] << 7) + (col << 1));
            union { unsigned u; float f; } flo, fhi;
            flo.u = p << 16;
            fhi.u = p & 0xffff0000u;
            acc.x += s * flo.f;
            acc.y += s * fhi.f;
            dn += s;
        }
        __syncthreads();
    }

    red[slot][col] = acc;
    if (col == 0) dred[slot] = dn;
    __syncthreads();
    if (tid < 64) {
        float2 a0 = red[0][tid], a1 = red[1][tid], a2 = red[2][tid], a3 = red[3][tid];
        float denom = dred[0] + dred[1] + dred[2] + dred[3];
        float2 o = make_float2(0.f, 0.f);
        if (end > start) {
            o.x = (a0.x + a1.x + a2.x + a3.x) / denom;
            o.y = (a0.y + a1.y + a2.y + a3.y) / denom;
        }
        *(float2*)&out[((size_t)n << 7) + (tid << 1)] = o;
    }
}

extern "C" void kernel_launch(void* const* d_in, const int* in_sizes, int n_in,
                              void* d_out, int out_size, void* d_ws, size_t ws_size,
                              hipStream_t stream) {
    const float* X     = (const float*)d_in[0];   // 50000 x 128
    const int*   edges = (const int*)d_in[1];     // 800000 x 2 (src,dst), src sorted
    const float* W     = (const float*)d_in[2];   // 128 x 128
    const float* ka    = (const float*)d_in[3];   // 256 x 1

    char* ws = (char*)d_ws;
    unsigned short* h = (unsigned short*)ws;                       // 12.8 MB bf16
    float* a_src = (float*)(ws + (size_t)N_NODES * D * 2);         // 200 KB
    float* a_dst = a_src + N_NODES;                                // 200 KB
    float* out = (float*)d_out;

    kh<<<(N_NODES + TM - 1) / TM, 256, 0, stream>>>(X, W, ka, h, a_src, a_dst, N_NODES);
    k3<<<N_NODES, 256, 0, stream>>>(edges, h, a_src, a_dst, out);
}

// Round 3
// 151.259 us; speedup vs baseline: 2.1588x; 2.1588x over previous
//
#include <hip/hip_runtime.h>

#define N_NODES 50000
#define N_EDGES 800000
#define D 128
#define TM 128

__device__ __forceinline__ unsigned short f2bf(float f) {
    union { float f; unsigned u; } v; v.f = f;
    return (unsigned short)((v.u + 0x7fffu + ((v.u >> 16) & 1u)) >> 16);
}
__device__ __forceinline__ float bflo(unsigned u) {
    union { unsigned u; float f; } c; c.u = u << 16; return c.f;
}
__device__ __forceinline__ float bfhi(unsigned u) {
    union { unsigned u; float f; } c; c.u = u & 0xffff0000u; return c.f;
}

// ---------------- K1: row_ptr[n] = lower_bound(src, n) ----------------------
__global__ void k1_rowptr(const int* __restrict__ edges, int* __restrict__ row_ptr) {
    int n = blockIdx.x * blockDim.x + threadIdx.x;
    if (n > N_NODES) return;
    int lo = 0, hi = N_EDGES;
    while (lo < hi) {
        int mid = (lo + hi) >> 1;
        if (edges[2 * mid] < n) lo = mid + 1; else hi = mid;
    }
    row_ptr[n] = lo;
}

// ---------------- KH: h_bf16 = X @ W (fp32 accum); a_src/a_dst epilogue -----
// LDS: As only (64 KB) -> 2 blocks/CU. W streams from global (L1/L2-hot).
__global__ __launch_bounds__(256) void kh(const float* __restrict__ X,
                                          const float* __restrict__ W,
                                          const float* __restrict__ ka,
                                          unsigned short* __restrict__ h,
                                          float* __restrict__ a_src,
                                          float* __restrict__ a_dst,
                                          int n_rows) {
    __shared__ float As[TM * D];     // [r][k], 64 KB
    __shared__ float kas[2 * D];
    int tid = threadIdx.x;
    int row0 = blockIdx.x * TM;

    kas[tid] = ka[tid];
    for (int i = tid; i < TM * D / 4; i += 256) {
        int r = i >> 5;
        int gr = row0 + r;
        float4 v = make_float4(0.f, 0.f, 0.f, 0.f);
        if (gr < n_rows) v = ((const float4*)(X + (size_t)gr * D))[i & 31];
        ((float4*)As)[i] = v;
    }
    __syncthreads();

    int cg = tid & 15;          // 16 col groups x 8 cols
    int rg = tid >> 4;          // 16 row groups x 8 rows
    int c0 = cg * 8;
    int r0 = rg * 8;
    float acc[8][8];
#pragma unroll
    for (int i = 0; i < 8; ++i)
#pragma unroll
        for (int j = 0; j < 8; ++j) acc[i][j] = 0.f;

    for (int k = 0; k < D; k += 4) {
        float4 av[8];
#pragma unroll
        for (int i = 0; i < 8; ++i)
            av[i] = *(const float4*)&As[(r0 + i) * D + k];
#pragma unroll
        for (int kk = 0; kk < 4; ++kk) {
            float4 wlo = *(const float4*)(W + (k + kk) * D + c0);
            float4 whi = *(const float4*)(W + (k + kk) * D + c0 + 4);
            float wv[8] = {wlo.x, wlo.y, wlo.z, wlo.w, whi.x, whi.y, whi.z, whi.w};
#pragma unroll
            for (int i = 0; i < 8; ++i) {
                float a = (kk == 0) ? av[i].x : (kk == 1) ? av[i].y
                        : (kk == 2) ? av[i].z : av[i].w;
#pragma unroll
                for (int j = 0; j < 8; ++j) acc[i][j] += a * wv[j];
            }
        }
    }

    // epilogue: bf16 h + per-row attention dots
#pragma unroll
    for (int i = 0; i < 8; ++i) {
        int row = row0 + r0 + i;
        float ps = 0.f, pd = 0.f;
#pragma unroll
        for (int j = 0; j < 8; ++j) {
            ps += acc[i][j] * kas[c0 + j];
            pd += acc[i][j] * kas[D + c0 + j];
        }
        for (int off = 8; off > 0; off >>= 1) {
            ps += __shfl_down(ps, off, 16);
            pd += __shfl_down(pd, off, 16);
        }
        if (row < n_rows) {
            union { unsigned short us[8]; uint4 q; } pk;
#pragma unroll
            for (int j = 0; j < 8; ++j) pk.us[j] = f2bf(acc[i][j]);
            *(uint4*)&h[(size_t)row * D + c0] = pk.q;
            if (cg == 0) { a_src[row] = ps; a_dst[row] = pd; }
        }
    }
}

// ---------------- K3: wave-per-node, barrier-free segment gather ------------
// 4 nodes per 256-thread block. Scores live in registers, broadcast via shfl.
// Each j-iter: 4 edges, lane-quarter q handles edge j+q, 16 lanes x 16B row read.
__global__ __launch_bounds__(256) void k3(const int* __restrict__ edges,
                                          const int* __restrict__ row_ptr,
                                          const unsigned short* __restrict__ h,
                                          const float* __restrict__ a_src,
                                          const float* __restrict__ a_dst,
                                          float* __restrict__ out) {
    int node = blockIdx.x * 4 + (threadIdx.x >> 6);
    if (node >= N_NODES) return;
    int lane = threadIdx.x & 63;
    int q = lane >> 4;          // quarter-wave 0..3
    int l16 = lane & 15;        // 16 lanes x 8 cols cover a 128-col row

    int start = row_ptr[node], end = row_ptr[node + 1];
    float asn = a_src[node];

    float4 accA = make_float4(0.f, 0.f, 0.f, 0.f);
    float4 accB = make_float4(0.f, 0.f, 0.f, 0.f);
    float dn = 0.f;

    for (int base = start; base < end; base += 64) {
        int cnt = min(64, end - base);
        int d = 0; float s = 0.f;
        if (lane < cnt) {
            d = edges[2 * (base + lane) + 1];
            float lg = asn + a_dst[d];
            lg = (lg >= 0.f) ? lg : 0.2f * lg;      // leaky_relu 0.2
            lg = fminf(fmaxf(lg, -2.f), 2.f);       // clip
            s = __expf(lg);
        }
        for (int j = 0; j < cnt; j += 4) {
            int slot = j + q;                        // <= 63 always
            float sj = __shfl(s, slot, 64);          // 0 for tail slots
            int   dj = __shfl(d, slot, 64);
            uint4 p = *(const uint4*)(h + ((size_t)dj << 7) + (l16 << 3));
            accA.x += sj * bflo(p.x); accA.y += sj * bfhi(p.x);
            accA.z += sj * bflo(p.y); accA.w += sj * bfhi(p.y);
            accB.x += sj * bflo(p.z); accB.y += sj * bfhi(p.z);
            accB.z += sj * bflo(p.w); accB.w += sj * bfhi(p.w);
            dn += sj;
        }
    }

    // fold the 4 quarter-waves (xor32 then xor16): every lane ends with totals
    float vals[9] = {accA.x, accA.y, accA.z, accA.w,
                     accB.x, accB.y, accB.z, accB.w, dn};
#pragma unroll
    for (int m = 32; m >= 16; m >>= 1)
#pragma unroll
        for (int i = 0; i < 9; ++i) vals[i] += __shfl_xor(vals[i], m, 64);

    if (q == 0) {
        float inv = (end > start) ? 1.f / vals[8] : 0.f;
        float4 o0 = make_float4(vals[0] * inv, vals[1] * inv, vals[2] * inv, vals[3] * inv);
        float4 o1 = make_float4(vals[4] * inv, vals[5] * inv, vals[6] * inv, vals[7] * inv);
        float* op = out + (size_t)node * D + l16 * 8;
        *(float4*)op = o0;
        *(float4*)(op + 4) = o1;
    }
}

extern "C" void kernel_launch(void* const* d_in, const int* in_sizes, int n_in,
                              void* d_out, int out_size, void* d_ws, size_t ws_size,
                              hipStream_t stream) {
    const float* X     = (const float*)d_in[0];   // 50000 x 128
    const int*   edges = (const int*)d_in[1];     // 800000 x 2 (src,dst), src sorted
    const float* W     = (const float*)d_in[2];   // 128 x 128
    const float* ka    = (const float*)d_in[3];   // 256 x 1

    char* ws = (char*)d_ws;
    unsigned short* h = (unsigned short*)ws;                        // 12.8 MB bf16
    float* a_src   = (float*)(ws + (size_t)N_NODES * D * 2);        // 200 KB
    float* a_dst   = a_src + N_NODES;                               // 200 KB
    int*   row_ptr = (int*)(a_dst + N_NODES);                       // 50001 ints
    float* out = (float*)d_out;

    k1_rowptr<<<(N_NODES + 1 + 255) / 256, 256, 0, stream>>>(edges, row_ptr);
    kh<<<(N_NODES + TM - 1) / TM, 256, 0, stream>>>(X, W, ka, h, a_src, a_dst, N_NODES);
    k3<<<(N_NODES + 3) / 4, 256, 0, stream>>>(edges, row_ptr, h, a_src, a_dst, out);
}

// Round 4
// 134.266 us; speedup vs baseline: 2.4320x; 1.1266x over previous
//
#include <hip/hip_runtime.h>

#define N_NODES 50000
#define N_EDGES 800000
#define D 128
#define LDA 136   // padded LDS row stride in shorts: +4 banks/row -> 2-way alias (free)

typedef __attribute__((ext_vector_type(8))) short bf16x8;
typedef __attribute__((ext_vector_type(4))) float f32x4;

__device__ __forceinline__ unsigned short f2bf(float f) {
    union { float f; unsigned u; } v; v.f = f;
    return (unsigned short)((v.u + 0x7fffu + ((v.u >> 16) & 1u)) >> 16);
}
__device__ __forceinline__ float bflo(unsigned u) {
    union { unsigned u; float f; } c; c.u = u << 16; return c.f;
}
__device__ __forceinline__ float bfhi(unsigned u) {
    union { unsigned u; float f; } c; c.u = u & 0xffff0000u; return c.f;
}

// ---------------- K1: row_ptr searches + Wt (bf16 transpose) + u,v ----------
#define NB_SEARCH 196
__global__ void k1_prep(const int* __restrict__ edges, const float* __restrict__ W,
                        const float* __restrict__ ka, int* __restrict__ row_ptr,
                        unsigned short* __restrict__ Wt,
                        float* __restrict__ u, float* __restrict__ v) {
    int b = blockIdx.x, tid = threadIdx.x;
    if (b < NB_SEARCH) {                       // lower_bound(src, n)
        int n = b * 256 + tid;
        if (n > N_NODES) return;
        int lo = 0, hi = N_EDGES;
        while (lo < hi) {
            int mid = (lo + hi) >> 1;
            if (edges[2 * mid] < n) lo = mid + 1; else hi = mid;
        }
        row_ptr[n] = lo;
    } else if (b < NB_SEARCH + 8) {            // Wt[n][k] = bf16(W[k][n])
        int bi = b - NB_SEARCH;
        for (int i = tid; i < 16 * D; i += 256) {
            int n = bi * 16 + (i >> 7), k = i & 127;
            Wt[n * D + k] = f2bf(W[k * D + n]);
        }
    } else {                                   // u = W@ka[0:128], v = W@ka[128:256]
        int k = tid & 127;
        const float* kap = ka + ((tid >> 7) ? D : 0);
        float s = 0.f;
        for (int j = 0; j < D; ++j) s += W[k * D + j] * kap[j];
        if (tid < 128) u[k] = s; else v[k] = s;
    }
}

// ---------------- KH: h_bf16 = bf16(X) @ bf16(W) via MFMA; fp32 a_src/a_dst -
__global__ __launch_bounds__(256) void kh(const float* __restrict__ X,
                                          const unsigned short* __restrict__ Wt,
                                          const float* __restrict__ u,
                                          const float* __restrict__ v,
                                          unsigned short* __restrict__ h,
                                          float* __restrict__ a_src,
                                          float* __restrict__ a_dst) {
    __shared__ unsigned short As[128 * LDA];   // [m][k], 34.8 KB
    __shared__ unsigned short Bs[128 * LDA];   // [n][k], 34.8 KB
    int tid = threadIdx.x;
    int row0 = blockIdx.x * 128;

    for (int i = tid; i < 2048; i += 256) {    // Bs <- Wt (already bf16, n-major)
        int r = i >> 4, c = i & 15;
        *(uint4*)&Bs[r * LDA + c * 8] = *(const uint4*)&Wt[r * D + c * 8];
    }
    for (int i = tid; i < 2048; i += 256) {    // As <- bf16(X tile)
        int r = i >> 4, c = i & 15;
        int gr = row0 + r;
        union { unsigned short us[8]; uint4 q; } pk;
        if (gr < N_NODES) {
            const float* xp = X + (size_t)gr * D + c * 8;
#pragma unroll
            for (int j = 0; j < 8; ++j) pk.us[j] = f2bf(xp[j]);
        } else pk.q = make_uint4(0u, 0u, 0u, 0u);
        *(uint4*)&As[r * LDA + c * 8] = pk.q;
    }
    __syncthreads();

    int wave = tid >> 6, lane = tid & 63;
    int m16 = lane & 15, quad = lane >> 4;
    int wr0 = wave * 32;                       // 2 row-tiles per wave
    f32x4 acc[2][8];
#pragma unroll
    for (int i = 0; i < 2; ++i)
#pragma unroll
        for (int j = 0; j < 8; ++j) acc[i][j] = (f32x4){0.f, 0.f, 0.f, 0.f};

    for (int k0 = 0; k0 < D; k0 += 32) {
        bf16x8 a0 = *(const bf16x8*)&As[(wr0 + m16) * LDA + k0 + quad * 8];
        bf16x8 a1 = *(const bf16x8*)&As[(wr0 + 16 + m16) * LDA + k0 + quad * 8];
#pragma unroll
        for (int j = 0; j < 8; ++j) {
            bf16x8 bf = *(const bf16x8*)&Bs[(j * 16 + m16) * LDA + k0 + quad * 8];
            acc[0][j] = __builtin_amdgcn_mfma_f32_16x16x32_bf16(a0, bf, acc[0][j], 0, 0, 0);
            acc[1][j] = __builtin_amdgcn_mfma_f32_16x16x32_bf16(a1, bf, acc[1][j], 0, 0, 0);
        }
    }

    // h store: C/D layout col=lane&15, row=quad*4+reg (m89-verified)
#pragma unroll
    for (int i = 0; i < 2; ++i)
#pragma unroll
        for (int j = 0; j < 8; ++j)
#pragma unroll
            for (int r = 0; r < 4; ++r) {
                int row = row0 + wr0 + i * 16 + quad * 4 + r;
                if (row < N_NODES)
                    h[(size_t)row * D + j * 16 + m16] = f2bf(acc[i][j][r]);
            }

    // fp32 attention dots from global X (L1-hot): 2 threads per row
    int rr = tid >> 1, hf = tid & 1;
    int grow = row0 + rr;
    if (grow < N_NODES) {
        const float* xp = X + (size_t)grow * D + hf * 64;
        float ps = 0.f, pd = 0.f;
        for (int jj = 0; jj < 64; jj += 4) {
            float4 xv = *(const float4*)(xp + jj);
            float4 uv = *(const float4*)(u + hf * 64 + jj);
            float4 vv = *(const float4*)(v + hf * 64 + jj);
            ps += xv.x * uv.x + xv.y * uv.y + xv.z * uv.z + xv.w * uv.w;
            pd += xv.x * vv.x + xv.y * vv.y + xv.z * vv.z + xv.w * vv.w;
        }
        ps += __shfl_xor(ps, 1, 64);
        pd += __shfl_xor(pd, 1, 64);
        if (hf == 0) { a_src[grow] = ps; a_dst[grow] = pd; }
    }
}

// ---------------- K3: wave-per-node gather, 2 loads in flight ---------------
__global__ __launch_bounds__(256) void k3(const int* __restrict__ edges,
                                          const int* __restrict__ row_ptr,
                                          const unsigned short* __restrict__ h,
                                          const float* __restrict__ a_src,
                                          const float* __restrict__ a_dst,
                                          float* __restrict__ out) {
    int node = blockIdx.x * 4 + (threadIdx.x >> 6);
    if (node >= N_NODES) return;
    int lane = threadIdx.x & 63;
    int q = lane >> 4;          // quarter-wave 0..3
    int l16 = lane & 15;        // 16 lanes x 8 cols cover a 128-col row

    int start = row_ptr[node], end = row_ptr[node + 1];
    float asn = a_src[node];

    float4 accA = make_float4(0.f, 0.f, 0.f, 0.f);
    float4 accB = make_float4(0.f, 0.f, 0.f, 0.f);
    float dn = 0.f;

    for (int base = start; base < end; base += 64) {
        int cnt = min(64, end - base);
        int d = 0; float s = 0.f;
        if (lane < cnt) {
            d = edges[2 * (base + lane) + 1];
            float lg = asn + a_dst[d];
            lg = (lg >= 0.f) ? lg : 0.2f * lg;      // leaky_relu 0.2
            lg = fminf(fmaxf(lg, -2.f), 2.f);       // clip
            s = __expf(lg);
        }
        for (int j = 0; j < cnt; j += 8) {          // 8 edges per iter, 2 loads/lane
            float s0 = __shfl(s, j + q, 64);
            int   d0 = __shfl(d, j + q, 64);
            float s1 = __shfl(s, j + q + 4, 64);
            int   d1 = __shfl(d, j + q + 4, 64);
            uint4 p0 = *(const uint4*)(h + ((size_t)d0 << 7) + (l16 << 3));
            uint4 p1 = *(const uint4*)(h + ((size_t)d1 << 7) + (l16 << 3));
            accA.x += s0 * bflo(p0.x); accA.y += s0 * bfhi(p0.x);
            accA.z += s0 * bflo(p0.y); accA.w += s0 * bfhi(p0.y);
            accB.x += s0 * bflo(p0.z); accB.y += s0 * bfhi(p0.z);
            accB.z += s0 * bflo(p0.w); accB.w += s0 * bfhi(p0.w);
            accA.x += s1 * bflo(p1.x); accA.y += s1 * bfhi(p1.x);
            accA.z += s1 * bflo(p1.y); accA.w += s1 * bfhi(p1.y);
            accB.x += s1 * bflo(p1.z); accB.y += s1 * bfhi(p1.z);
            accB.z += s1 * bflo(p1.w); accB.w += s1 * bfhi(p1.w);
            dn += s0 + s1;
        }
    }

    float vals[9] = {accA.x, accA.y, accA.z, accA.w,
                     accB.x, accB.y, accB.z, accB.w, dn};
#pragma unroll
    for (int m = 32; m >= 16; m >>= 1)
#pragma unroll
        for (int i = 0; i < 9; ++i) vals[i] += __shfl_xor(vals[i], m, 64);

    if (q == 0) {
        float inv = (end > start) ? 1.f / vals[8] : 0.f;
        float4 o0 = make_float4(vals[0] * inv, vals[1] * inv, vals[2] * inv, vals[3] * inv);
        float4 o1 = make_float4(vals[4] * inv, vals[5] * inv, vals[6] * inv, vals[7] * inv);
        float* op = out + (size_t)node * D + l16 * 8;
        *(float4*)op = o0;
        *(float4*)(op + 4) = o1;
    }
}

extern "C" void kernel_launch(void* const* d_in, const int* in_sizes, int n_in,
                              void* d_out, int out_size, void* d_ws, size_t ws_size,
                              hipStream_t stream) {
    const float* X     = (const float*)d_in[0];   // 50000 x 128
    const int*   edges = (const int*)d_in[1];     // 800000 x 2 (src,dst), src sorted
    const float* W     = (const float*)d_in[2];   // 128 x 128
    const float* ka    = (const float*)d_in[3];   // 256 x 1

    char* ws = (char*)d_ws;
    unsigned short* h  = (unsigned short*)ws;                       // 12.8 MB bf16
    float* a_src   = (float*)(ws + (size_t)N_NODES * D * 2);        // 200 KB
    float* a_dst   = a_src + N_NODES;                               // 200 KB
    int*   row_ptr = (int*)(a_dst + N_NODES);                       // ~200 KB
    unsigned short* Wt = (unsigned short*)(row_ptr + N_NODES + 4);  // 32 KB bf16
    float* u = (float*)(Wt + D * D);                                // 512 B
    float* v = u + D;                                               // 512 B
    float* out = (float*)d_out;

    k1_prep<<<NB_SEARCH + 9, 256, 0, stream>>>(edges, W, ka, row_ptr, Wt, u, v);
    kh<<<(N_NODES + 127) / 128, 256, 0, stream>>>(X, Wt, u, v, h, a_src, a_dst);
    k3<<<(N_NODES + 3) / 4, 256, 0, stream>>>(edges, row_ptr, h, a_src, a_dst, out);
}

// Round 5
// 127.524 us; speedup vs baseline: 2.5606x; 1.0529x over previous
//
#include <hip/hip_runtime.h>

#define N_NODES 50000
#define N_EDGES 800000
#define D 128
#define LDA 136   // padded LDS row stride in shorts (+4 banks/row -> 2-way alias, free)

#define SEARCH_BLOCKS 196   // ceil(50001/256)
#define GEMM_BLOCKS   391   // ceil(50000/128)

typedef __attribute__((ext_vector_type(8))) short bf16x8;
typedef __attribute__((ext_vector_type(4))) float f32x4;

__device__ __forceinline__ unsigned short f2bf(float f) {
    union { float f; unsigned u; } v; v.f = f;
    return (unsigned short)((v.u + 0x7fffu + ((v.u >> 16) & 1u)) >> 16);
}
__device__ __forceinline__ float bflo(unsigned u) {
    union { unsigned u; float f; } c; c.u = u << 16; return c.f;
}
__device__ __forceinline__ float bfhi(unsigned u) {
    union { unsigned u; float f; } c; c.u = u & 0xffff0000u; return c.f;
}

// ------- KH: fused row_ptr searches + (h = bf16(X)@bf16(W) MFMA, a_src/a_dst) ----
// Blocks [0, SEARCH_BLOCKS): lower_bound(src, n) -> row_ptr. Independent of GEMM.
// Blocks [SEARCH_BLOCKS, SEARCH_BLOCKS+GEMM_BLOCKS): 128-row GEMM tile.
__global__ __launch_bounds__(256) void kh_fused(const float* __restrict__ X,
                                                const int* __restrict__ edges,
                                                const float* __restrict__ W,
                                                const float* __restrict__ ka,
                                                unsigned short* __restrict__ h,
                                                float* __restrict__ a_src,
                                                float* __restrict__ a_dst,
                                                int* __restrict__ row_ptr) {
    __shared__ unsigned short As[128 * LDA];   // [m][k], 34.8 KB
    __shared__ unsigned short Bs[128 * LDA];   // [n][k], 34.8 KB
    __shared__ float kas[2 * D];               // 1 KB
    int b = blockIdx.x, tid = threadIdx.x;

    if (b < SEARCH_BLOCKS) {                   // row_ptr[n] = lower_bound(src, n)
        int n = b * 256 + tid;
        if (n > N_NODES) return;
        int lo = 0, hi = N_EDGES;
        while (lo < hi) {
            int mid = (lo + hi) >> 1;
            if (edges[2 * mid] < n) lo = mid + 1; else hi = mid;
        }
        row_ptr[n] = lo;
        return;
    }

    int row0 = (b - SEARCH_BLOCKS) * 128;
    kas[tid] = ka[tid];
    // Bs <- bf16(W^T): thread reads W[k][n4..n4+3] coalesced, scatters 4 u16.
    for (int i = tid; i < 128 * 32; i += 256) {
        int k = i >> 5, n4 = (i & 31) * 4;
        float4 w = *(const float4*)(W + k * D + n4);
        Bs[(n4 + 0) * LDA + k] = f2bf(w.x);
        Bs[(n4 + 1) * LDA + k] = f2bf(w.y);
        Bs[(n4 + 2) * LDA + k] = f2bf(w.z);
        Bs[(n4 + 3) * LDA + k] = f2bf(w.w);
    }
    // As <- bf16(X tile)
    for (int i = tid; i < 2048; i += 256) {
        int r = i >> 4, c = i & 15;
        int gr = row0 + r;
        union { unsigned short us[8]; uint4 q; } pk;
        if (gr < N_NODES) {
            const float* xp = X + (size_t)gr * D + c * 8;
#pragma unroll
            for (int j = 0; j < 8; ++j) pk.us[j] = f2bf(xp[j]);
        } else pk.q = make_uint4(0u, 0u, 0u, 0u);
        *(uint4*)&As[r * LDA + c * 8] = pk.q;
    }
    __syncthreads();

    int wave = tid >> 6, lane = tid & 63;
    int m16 = lane & 15, quad = lane >> 4;
    int wr0 = wave * 32;                       // 2 row-tiles per wave
    f32x4 acc[2][8];
#pragma unroll
    for (int i = 0; i < 2; ++i)
#pragma unroll
        for (int j = 0; j < 8; ++j) acc[i][j] = (f32x4){0.f, 0.f, 0.f, 0.f};

    for (int k0 = 0; k0 < D; k0 += 32) {
        bf16x8 a0 = *(const bf16x8*)&As[(wr0 + m16) * LDA + k0 + quad * 8];
        bf16x8 a1 = *(const bf16x8*)&As[(wr0 + 16 + m16) * LDA + k0 + quad * 8];
#pragma unroll
        for (int j = 0; j < 8; ++j) {
            bf16x8 bf = *(const bf16x8*)&Bs[(j * 16 + m16) * LDA + k0 + quad * 8];
            acc[0][j] = __builtin_amdgcn_mfma_f32_16x16x32_bf16(a0, bf, acc[0][j], 0, 0, 0);
            acc[1][j] = __builtin_amdgcn_mfma_f32_16x16x32_bf16(a1, bf, acc[1][j], 0, 0, 0);
        }
    }

    // h store: C/D layout col=lane&15, row=quad*4+reg (m89-verified)
#pragma unroll
    for (int i = 0; i < 2; ++i)
#pragma unroll
        for (int j = 0; j < 8; ++j)
#pragma unroll
            for (int r = 0; r < 4; ++r) {
                int row = row0 + wr0 + i * 16 + quad * 4 + r;
                if (row < N_NODES)
                    h[(size_t)row * D + j * 16 + m16] = f2bf(acc[i][j][r]);
            }

    // a_src/a_dst from fp32 accumulators: a_src[row] = sum_col h[row][col]*ka[col]
#pragma unroll
    for (int i = 0; i < 2; ++i)
#pragma unroll
        for (int r = 0; r < 4; ++r) {
            float ps = 0.f, pd = 0.f;
#pragma unroll
            for (int j = 0; j < 8; ++j) {
                float val = acc[i][j][r];
                ps += val * kas[j * 16 + m16];
                pd += val * kas[D + j * 16 + m16];
            }
            for (int off = 8; off > 0; off >>= 1) {
                ps += __shfl_down(ps, off, 16);
                pd += __shfl_down(pd, off, 16);
            }
            int row = row0 + wr0 + i * 16 + quad * 4 + r;
            if (m16 == 0 && row < N_NODES) { a_src[row] = ps; a_dst[row] = pd; }
        }
}

// ---------------- K3: wave-per-node gather, 4 loads in flight ---------------
__global__ __launch_bounds__(256) void k3(const int* __restrict__ edges,
                                          const int* __restrict__ row_ptr,
                                          const unsigned short* __restrict__ h,
                                          const float* __restrict__ a_src,
                                          const float* __restrict__ a_dst,
                                          float* __restrict__ out) {
    int node = blockIdx.x * 4 + (threadIdx.x >> 6);
    if (node >= N_NODES) return;
    int lane = threadIdx.x & 63;
    int q = lane >> 4;          // quarter-wave 0..3
    int l16 = lane & 15;        // 16 lanes x 8 cols cover a 128-col row

    int start = row_ptr[node], end = row_ptr[node + 1];
    float asn = a_src[node];

    float4 accA = make_float4(0.f, 0.f, 0.f, 0.f);
    float4 accB = make_float4(0.f, 0.f, 0.f, 0.f);
    float dn = 0.f;

    for (int base = start; base < end; base += 64) {
        int cnt = min(64, end - base);
        int d = 0; float s = 0.f;
        if (lane < cnt) {
            d = edges[2 * (base + lane) + 1];
            float lg = asn + a_dst[d];
            lg = (lg >= 0.f) ? lg : 0.2f * lg;      // leaky_relu 0.2
            lg = fminf(fmaxf(lg, -2.f), 2.f);       // clip
            s = __expf(lg);
        }
        for (int j = 0; j < cnt; j += 16) {         // 16 edges/iter, 4 loads/lane in flight
            float sj[4]; int dj[4];
#pragma unroll
            for (int t = 0; t < 4; ++t) {
                sj[t] = __shfl(s, j + q + 4 * t, 64);   // 0 for dead slots
                dj[t] = __shfl(d, j + q + 4 * t, 64);   // 0 for dead slots -> hot row 0
            }
            uint4 p[4];
#pragma unroll
            for (int t = 0; t < 4; ++t)
                p[t] = *(const uint4*)(h + ((size_t)dj[t] << 7) + (l16 << 3));
#pragma unroll
            for (int t = 0; t < 4; ++t) {
                float sv = sj[t];
                accA.x += sv * bflo(p[t].x); accA.y += sv * bfhi(p[t].x);
                accA.z += sv * bflo(p[t].y); accA.w += sv * bfhi(p[t].y);
                accB.x += sv * bflo(p[t].z); accB.y += sv * bfhi(p[t].z);
                accB.z += sv * bflo(p[t].w); accB.w += sv * bfhi(p[t].w);
                dn += sv;
            }
        }
    }

    float vals[9] = {accA.x, accA.y, accA.z, accA.w,
                     accB.x, accB.y, accB.z, accB.w, dn};
#pragma unroll
    for (int m = 32; m >= 16; m >>= 1)
#pragma unroll
        for (int i = 0; i < 9; ++i) vals[i] += __shfl_xor(vals[i], m, 64);

    if (q == 0) {
        float inv = (end > start) ? 1.f / vals[8] : 0.f;
        float4 o0 = make_float4(vals[0] * inv, vals[1] * inv, vals[2] * inv, vals[3] * inv);
        float4 o1 = make_float4(vals[4] * inv, vals[5] * inv, vals[6] * inv, vals[7] * inv);
        float* op = out + (size_t)node * D + l16 * 8;
        *(float4*)op = o0;
        *(float4*)(op + 4) = o1;
    }
}

extern "C" void kernel_launch(void* const* d_in, const int* in_sizes, int n_in,
                              void* d_out, int out_size, void* d_ws, size_t ws_size,
                              hipStream_t stream) {
    const float* X     = (const float*)d_in[0];   // 50000 x 128
    const int*   edges = (const int*)d_in[1];     // 800000 x 2 (src,dst), src sorted
    const float* W     = (const float*)d_in[2];   // 128 x 128
    const float* ka    = (const float*)d_in[3];   // 256 x 1

    char* ws = (char*)d_ws;
    unsigned short* h  = (unsigned short*)ws;                       // 12.8 MB bf16
    float* a_src   = (float*)(ws + (size_t)N_NODES * D * 2);        // 200 KB
    float* a_dst   = a_src + N_NODES;                               // 200 KB
    int*   row_ptr = (int*)(a_dst + N_NODES);                       // ~200 KB
    float* out = (float*)d_out;

    kh_fused<<<SEARCH_BLOCKS + GEMM_BLOCKS, 256, 0, stream>>>(
        X, edges, W, ka, h, a_src, a_dst, row_ptr);
    k3<<<(N_NODES + 3) / 4, 256, 0, stream>>>(edges, row_ptr, h, a_src, a_dst, out);
}